// Round 14
// baseline (167.886 us; speedup 1.0000x reference)
//
#include <hip/hip_runtime.h>
#include <math.h>
#include <stdint.h>

#define B_ 16
#define D_ 1024
#define T_ 4096
#define CS_ 1024
#define CD_ 8

// ---------- numpy-mimicking fp32 helpers ----------
__device__ __forceinline__ float f_tree8(const float r[8]) {
  return __fadd_rn(
      __fadd_rn(__fadd_rn(r[0], r[1]), __fadd_rn(r[2], r[3])),
      __fadd_rn(__fadd_rn(r[4], r[5]), __fadd_rn(r[6], r[7])));
}
__device__ __forceinline__ float f_sumsq8(const float x[8]) {
  float s[8];
#pragma unroll
  for (int k = 0; k < 8; ++k) s[k] = __fmul_rn(x[k], x[k]);
  return f_tree8(s);
}

// ---------- setup: normalize W_in, W_out, codebook; pack tables ----------
// ws layout:
//   WTd  : double[1024][8]   (W_in^T, fp32-rounded widened to f64)  @ 0      (65536 B)
//   cb16 : float [1024][16]  ({cbn[8], scb, pad})                   @ 65536  (65536 B)
//   wo16 : float [1024][16]  ({woutn[8], b_out, pad})               @ 131072 (65536 B)
//   lossp: float [256]                                              @ 196608 (1024 B)
__global__ __launch_bounds__(1024) void vq_setup(
    const float* __restrict__ cb, const float* __restrict__ g_in,
    const float* __restrict__ v_in, const float* __restrict__ g_out,
    const float* __restrict__ v_out, const float* __restrict__ b_out,
    double* __restrict__ WTd, float* __restrict__ cb16,
    float* __restrict__ wo16) {
  __shared__ float sv[8 * 1024];
  __shared__ float leafs[64];
  __shared__ float den[8];
  const int tid = threadIdx.x;

  for (int i = tid; i < 8 * 1024; i += 1024) sv[i] = v_in[i];
  __syncthreads();

  // numpy pairwise_sum(1024): 8 leaf blocks of 128 (8-accumulator pattern),
  // combined with the same binary tree as tree8.
  if (tid < 64) {
    const int c = tid >> 3, l = tid & 7;
    const float* a = sv + c * 1024 + l * 128;
    float r[8];
#pragma unroll
    for (int k = 0; k < 8; ++k) r[k] = __fmul_rn(a[k], a[k]);
    for (int i = 8; i < 128; i += 8) {
#pragma unroll
      for (int k = 0; k < 8; ++k)
        r[k] = __fadd_rn(r[k], __fmul_rn(a[i + k], a[i + k]));
    }
    leafs[c * 8 + l] = f_tree8(r);
  }
  __syncthreads();
  if (tid < 8) {
    const float* L = leafs + tid * 8;
    float lr[8];
#pragma unroll
    for (int k = 0; k < 8; ++k) lr[k] = L[k];
    const float s = f_tree8(lr);
    den[tid] = fmaxf(__fsqrt_rn(s), 1e-12f);
  }
  __syncthreads();

  if (tid < 1024) {
#pragma unroll
    for (int c = 0; c < 8; ++c) {
      const float w = __fdiv_rn(__fmul_rn(g_in[c], sv[c * 1024 + tid]), den[c]);
      WTd[tid * 8 + c] = (double)w;
    }
    {
      const float* cr = cb + tid * 8;
      float q[8];
#pragma unroll
      for (int c = 0; c < 8; ++c) q[c] = cr[c];
      const float nn = f_sumsq8(q);
      const float dd = fmaxf(__fsqrt_rn(nn), 1e-12f);
      float qn[8];
#pragma unroll
      for (int c = 0; c < 8; ++c) {
        qn[c] = __fdiv_rn(q[c], dd);
        cb16[tid * 16 + c] = qn[c];
      }
      cb16[tid * 16 + 8] = f_sumsq8(qn);
#pragma unroll
      for (int c = 9; c < 16; ++c) cb16[tid * 16 + c] = 0.f;
    }
    {
      const float* vr = v_out + tid * 8;
      float w[8];
#pragma unroll
      for (int c = 0; c < 8; ++c) w[c] = vr[c];
      const float n2 = f_sumsq8(w);
      const float d2 = fmaxf(__fsqrt_rn(n2), 1e-12f);
      const float go = g_out[tid];
#pragma unroll
      for (int c = 0; c < 8; ++c)
        wo16[tid * 16 + c] = __fdiv_rn(__fmul_rn(go, w[c]), d2);
      wo16[tid * 16 + 8] = b_out[tid];
#pragma unroll
      for (int c = 9; c < 16; ++c) wo16[tid * 16 + c] = 0.f;
    }
  }
}

// ---------- main kernel (R14: 256-t tile, float4 both streams) ----------
// Grid: 256 blocks x 1024 threads (16 waves). Block owns 256 consecutive t
// of one b; each LANE owns 4 consecutive t (float4 z loads / out stores =
// 1 KB per wave-instruction, the G2/G13 coalescing sweet spot; R7-R13 were
// stuck at 2.66 TB/s with 512-B float2 segments on both streams).
// Wave q covers the same 256 t but d/code SLICE [q*64, (q+1)*64).
// W via uniform s_load (R10-proven). acc[4t][8ch] f64 = 64 VGPR; bounds
// (1024,4) caps at 128 so prefetch depth can materialize.
// Accumulation order per t identical to R10 (64-d ascending within slice,
// slices combined ascending, strict-< first-min) -> indices bit-stable.
__global__ __launch_bounds__(1024, 4) void vq_main(
    const float* __restrict__ z, const float* __restrict__ cbraw,
    const float* __restrict__ b_in, const double* __restrict__ WTd,
    const float* __restrict__ cb16, const float* __restrict__ wo16,
    float* __restrict__ out, float* __restrict__ oidx,
    float* __restrict__ lossp) {
  __shared__ double accb[8704];  // 68 KB: combine (4 passes) + candidates
  const int tid = threadIdx.x;
  const int q0 = __builtin_amdgcn_readfirstlane(tid >> 6);  // wave 0..15
  const int tl = tid & 63;
  const int blk = blockIdx.x;  // 256 = 16 b * 16 tiles
  const int b = blk >> 4;
  const int tile = blk & 15;
  const int t0 = tile * 256 + tl * 4;  // this lane's 4-t group

  // ---- phase 1: partial z_e in f64 over this wave's 64-d slice ----
  const float4* zp4 =
      (const float4*)(z + ((size_t)b * D_ + (size_t)q0 * 64) * T_ + t0);
  const double* wd = WTd + (size_t)q0 * 512;  // uniform -> s_load

  double a0[8], a1[8], a2[8], a3[8];
#pragma unroll
  for (int c = 0; c < 8; ++c) { a0[c] = 0.0; a1[c] = 0.0; a2[c] = 0.0; a3[c] = 0.0; }

  float4 zA[4], zB[4];
#pragma unroll
  for (int u = 0; u < 4; ++u) zA[u] = zp4[(size_t)u * (T_ / 4)];

#pragma unroll
  for (int dc = 0; dc < 64; dc += 8) {
    // prefetch group B (rows dc+4 .. dc+7)
#pragma unroll
    for (int u = 0; u < 4; ++u)
      zB[u] = zp4[(size_t)(dc + 4 + u) * (T_ / 4)];
    // compute group A (rows dc .. dc+3)
#pragma unroll
    for (int u = 0; u < 4; ++u) {
      const double* w = wd + (size_t)(dc + u) * 8;
      const double zx = (double)zA[u].x, zy = (double)zA[u].y;
      const double zz = (double)zA[u].z, zw = (double)zA[u].w;
#pragma unroll
      for (int c = 0; c < 8; ++c) {
        a0[c] = fma(zx, w[c], a0[c]);
        a1[c] = fma(zy, w[c], a1[c]);
        a2[c] = fma(zz, w[c], a2[c]);
        a3[c] = fma(zw, w[c], a3[c]);
      }
    }
    // prefetch group A for next chunk
    if (dc + 8 < 64) {
#pragma unroll
      for (int u = 0; u < 4; ++u)
        zA[u] = zp4[(size_t)(dc + 8 + u) * (T_ / 4)];
    }
    // compute group B
#pragma unroll
    for (int u = 0; u < 4; ++u) {
      const double* w = wd + (size_t)(dc + 4 + u) * 8;
      const double zx = (double)zB[u].x, zy = (double)zB[u].y;
      const double zz = (double)zB[u].z, zw = (double)zB[u].w;
#pragma unroll
      for (int c = 0; c < 8; ++c) {
        a0[c] = fma(zx, w[c], a0[c]);
        a1[c] = fma(zy, w[c], a1[c]);
        a2[c] = fma(zz, w[c], a2[c]);
        a3[c] = fma(zw, w[c], a3[c]);
      }
    }
  }

  // ---- 16-slice f64 combine: 4 passes x 2 channels through 64 KB.
  //      Wave 0 reduces (ascending slice order, identical to R10),
  //      broadcast via disjoint totb ----
  double2* accb2 = (double2*)accb;       // partials: [0, 4096) double2
  double2* totb = accb2 + 4096;          // tot: [4096, 4352) double2
  double t_0[8], t_1[8], t_2[8], t_3[8];
#pragma unroll
  for (int pass = 0; pass < 4; ++pass) {
    const int c0 = pass * 2;
#pragma unroll
    for (int cc = 0; cc < 2; ++cc) {
      double2 p01, p23;
      p01.x = (cc ? a0[c0 + 1] : a0[c0]);
      p01.y = (cc ? a1[c0 + 1] : a1[c0]);
      p23.x = (cc ? a2[c0 + 1] : a2[c0]);
      p23.y = (cc ? a3[c0 + 1] : a3[c0]);
      accb2[(cc * 2 + 0) * 1024 + tid] = p01;
      accb2[(cc * 2 + 1) * 1024 + tid] = p23;
    }
    __syncthreads();
    if (tid < 64) {
#pragma unroll
      for (int r = 0; r < 4; ++r) {  // r = cc*2 + pair
        const double2* row = accb2 + r * 1024 + tl;
        double2 s = row[0];
#pragma unroll
        for (int qq = 1; qq < 16; ++qq) {
          const double2 v = row[qq * 64];
          s.x = s.x + v.x;  // ascending slice order (bit-identical to R10)
          s.y = s.y + v.y;
        }
        totb[r * 64 + tl] = s;
      }
    }
    __syncthreads();
#pragma unroll
    for (int cc = 0; cc < 2; ++cc) {
      const double2 s01 = totb[(cc * 2 + 0) * 64 + tl];
      const double2 s23 = totb[(cc * 2 + 1) * 64 + tl];
      t_0[c0 + cc] = s01.x; t_1[c0 + cc] = s01.y;
      t_2[c0 + cc] = s23.x; t_3[c0 + cc] = s23.y;
    }
    __syncthreads();  // totb/accb2 reuse next pass
  }

  // materialize fp32 z_e (+ b_in), normalize (numpy-mimicked), per t
  float e0[8], e1[8], e2[8], e3[8], en0[8], en1[8], en2[8], en3[8];
#pragma unroll
  for (int c = 0; c < 8; ++c) {
    e0[c] = __fadd_rn((float)t_0[c], b_in[c]);
    e1[c] = __fadd_rn((float)t_1[c], b_in[c]);
    e2[c] = __fadd_rn((float)t_2[c], b_in[c]);
    e3[c] = __fadd_rn((float)t_3[c], b_in[c]);
  }
  const float dn0 = fmaxf(__fsqrt_rn(f_sumsq8(e0)), 1e-12f);
  const float dn1 = fmaxf(__fsqrt_rn(f_sumsq8(e1)), 1e-12f);
  const float dn2 = fmaxf(__fsqrt_rn(f_sumsq8(e2)), 1e-12f);
  const float dn3 = fmaxf(__fsqrt_rn(f_sumsq8(e3)), 1e-12f);
#pragma unroll
  for (int c = 0; c < 8; ++c) {
    en0[c] = __fdiv_rn(e0[c], dn0);
    en1[c] = __fdiv_rn(e1[c], dn1);
    en2[c] = __fdiv_rn(e2[c], dn2);
    en3[c] = __fdiv_rn(e3[c], dn3);
  }
  const float se0 = f_sumsq8(en0), se1 = f_sumsq8(en1);
  const float se2 = f_sumsq8(en2), se3 = f_sumsq8(en3);

  // ---- phase 2: nearest code over this wave's 64-code slice ----
  const int j0 = q0 * 64;
  float b0 = INFINITY, b1 = INFINITY, b2 = INFINITY, b3 = INFINITY;
  int j_0 = j0, j_1 = j0, j_2 = j0, j_3 = j0;
  {
    const float* cbq = cb16 + (size_t)j0 * 16;  // uniform -> s_load
#pragma unroll 4
    for (int jj = 0; jj < 64; ++jj) {
      const float* row = cbq + jj * 16;
      const float4 lo = *(const float4*)(row);
      const float4 hi = *(const float4*)(row + 4);
      const float sc = row[8];
      float d0 = 0.f, d1 = 0.f, d2 = 0.f, d3 = 0.f;
      d0 = fmaf(en0[0], lo.x, d0); d1 = fmaf(en1[0], lo.x, d1);
      d2 = fmaf(en2[0], lo.x, d2); d3 = fmaf(en3[0], lo.x, d3);
      d0 = fmaf(en0[1], lo.y, d0); d1 = fmaf(en1[1], lo.y, d1);
      d2 = fmaf(en2[1], lo.y, d2); d3 = fmaf(en3[1], lo.y, d3);
      d0 = fmaf(en0[2], lo.z, d0); d1 = fmaf(en1[2], lo.z, d1);
      d2 = fmaf(en2[2], lo.z, d2); d3 = fmaf(en3[2], lo.z, d3);
      d0 = fmaf(en0[3], lo.w, d0); d1 = fmaf(en1[3], lo.w, d1);
      d2 = fmaf(en2[3], lo.w, d2); d3 = fmaf(en3[3], lo.w, d3);
      d0 = fmaf(en0[4], hi.x, d0); d1 = fmaf(en1[4], hi.x, d1);
      d2 = fmaf(en2[4], hi.x, d2); d3 = fmaf(en3[4], hi.x, d3);
      d0 = fmaf(en0[5], hi.y, d0); d1 = fmaf(en1[5], hi.y, d1);
      d2 = fmaf(en2[5], hi.y, d2); d3 = fmaf(en3[5], hi.y, d3);
      d0 = fmaf(en0[6], hi.z, d0); d1 = fmaf(en1[6], hi.z, d1);
      d2 = fmaf(en2[6], hi.z, d2); d3 = fmaf(en3[6], hi.z, d3);
      d0 = fmaf(en0[7], hi.w, d0); d1 = fmaf(en1[7], hi.w, d1);
      d2 = fmaf(en2[7], hi.w, d2); d3 = fmaf(en3[7], hi.w, d3);
      const float x0 = __fadd_rn(__fsub_rn(se0, __fmul_rn(2.0f, d0)), sc);
      const float x1 = __fadd_rn(__fsub_rn(se1, __fmul_rn(2.0f, d1)), sc);
      const float x2 = __fadd_rn(__fsub_rn(se2, __fmul_rn(2.0f, d2)), sc);
      const float x3 = __fadd_rn(__fsub_rn(se3, __fmul_rn(2.0f, d3)), sc);
      if (x0 < b0) { b0 = x0; j_0 = j0 + jj; }
      if (x1 < b1) { b1 = x1; j_1 = j0 + jj; }
      if (x2 < b2) { b2 = x2; j_2 = j0 + jj; }
      if (x3 < b3) { b3 = x3; j_3 = j0 + jj; }
    }
  }

  // ---- candidate combine: wave 0 scans (ascending qq, strict <), writes
  //      idx float4, broadcasts winners via ibuf ----
  float* df = (float*)accb;                     // 4 x 1024 f32 (16 KB)
  int* cj = (int*)((char*)accb + 16384);        // 4 x 1024 i32 (16 KB)
  int* ibuf = (int*)((char*)accb + 32768);      // 256 i32
  df[tid] = b0; df[1024 + tid] = b1; df[2048 + tid] = b2; df[3072 + tid] = b3;
  cj[tid] = j_0; cj[1024 + tid] = j_1; cj[2048 + tid] = j_2; cj[3072 + tid] = j_3;
  __syncthreads();

  if (tid < 64) {
    int win[4];
#pragma unroll
    for (int k = 0; k < 4; ++k) {
      const float* dk = df + k * 1024;
      const int* jk = cj + k * 1024;
      float bd = dk[tl];
      int bi = jk[tl];
#pragma unroll
      for (int qq = 1; qq < 16; ++qq) {
        const float dd = dk[qq * 64 + tl];
        const int jv = jk[qq * 64 + tl];
        if (dd < bd) { bd = dd; bi = jv; }  // strict <: low slice wins
      }
      win[k] = bi;
      ibuf[k * 64 + tl] = bi;
    }
    float4 iv;
    iv.x = (float)win[0]; iv.y = (float)win[1];
    iv.z = (float)win[2]; iv.w = (float)win[3];
    *(float4*)(oidx + (size_t)b * T_ + t0) = iv;
  }
  __syncthreads();
  const int bi0 = ibuf[tl], bi1 = ibuf[64 + tl];
  const int bi2 = ibuf[128 + tl], bi3 = ibuf[192 + tl];

  // raw codebook rows for loss + back-projection (divergent 32B gathers)
  float cq0[8], cq1[8], cq2[8], cq3[8];
  {
    const float* p0 = cbraw + (size_t)bi0 * 8;
    const float* p1 = cbraw + (size_t)bi1 * 8;
    const float* p2 = cbraw + (size_t)bi2 * 8;
    const float* p3 = cbraw + (size_t)bi3 * 8;
#pragma unroll
    for (int c = 0; c < 8; ++c) {
      cq0[c] = p0[c]; cq1[c] = p1[c]; cq2[c] = p2[c]; cq3[c] = p3[c];
    }
  }

  // ---- loss partial (wave 0 only) ----
  if (tid < 64) {
    float lsum = 0.f;
#pragma unroll
    for (int c = 0; c < 8; ++c) {
      const float f0 = __fsub_rn(e0[c], cq0[c]); lsum = fmaf(f0, f0, lsum);
    }
#pragma unroll
    for (int c = 0; c < 8; ++c) {
      const float f1 = __fsub_rn(e1[c], cq1[c]); lsum = fmaf(f1, f1, lsum);
    }
#pragma unroll
    for (int c = 0; c < 8; ++c) {
      const float f2 = __fsub_rn(e2[c], cq2[c]); lsum = fmaf(f2, f2, lsum);
    }
#pragma unroll
    for (int c = 0; c < 8; ++c) {
      const float f3 = __fsub_rn(e3[c], cq3[c]); lsum = fmaf(f3, f3, lsum);
    }
#pragma unroll
    for (int off = 32; off > 0; off >>= 1)
      lsum += __shfl_down(lsum, off, 64);
    if (tl == 0) lossp[blk] = lsum;
  }

  // ---- phase 3: out[b,d,t0..t0+3] over this wave's 64-d slice ----
  float4* op4 =
      (float4*)(out + ((size_t)b * D_ + (size_t)q0 * 64) * T_ + t0);
  const float* woq = wo16 + (size_t)q0 * 1024;  // uniform -> s_load
#pragma unroll 4
  for (int d = 0; d < 64; ++d) {
    const float* row = woq + d * 16;
    const float4 lo = *(const float4*)(row);
    const float4 hi = *(const float4*)(row + 4);
    const float bo = row[8];
    float d0 = 0.f, d1 = 0.f, d2 = 0.f, d3 = 0.f;
    d0 = fmaf(cq0[0], lo.x, d0); d1 = fmaf(cq1[0], lo.x, d1);
    d2 = fmaf(cq2[0], lo.x, d2); d3 = fmaf(cq3[0], lo.x, d3);
    d0 = fmaf(cq0[1], lo.y, d0); d1 = fmaf(cq1[1], lo.y, d1);
    d2 = fmaf(cq2[1], lo.y, d2); d3 = fmaf(cq3[1], lo.y, d3);
    d0 = fmaf(cq0[2], lo.z, d0); d1 = fmaf(cq1[2], lo.z, d1);
    d2 = fmaf(cq2[2], lo.z, d2); d3 = fmaf(cq3[2], lo.z, d3);
    d0 = fmaf(cq0[3], lo.w, d0); d1 = fmaf(cq1[3], lo.w, d1);
    d2 = fmaf(cq2[3], lo.w, d2); d3 = fmaf(cq3[3], lo.w, d3);
    d0 = fmaf(cq0[4], hi.x, d0); d1 = fmaf(cq1[4], hi.x, d1);
    d2 = fmaf(cq2[4], hi.x, d2); d3 = fmaf(cq3[4], hi.x, d3);
    d0 = fmaf(cq0[5], hi.y, d0); d1 = fmaf(cq1[5], hi.y, d1);
    d2 = fmaf(cq2[5], hi.y, d2); d3 = fmaf(cq3[5], hi.y, d3);
    d0 = fmaf(cq0[6], hi.z, d0); d1 = fmaf(cq1[6], hi.z, d1);
    d2 = fmaf(cq2[6], hi.z, d2); d3 = fmaf(cq3[6], hi.z, d3);
    d0 = fmaf(cq0[7], hi.w, d0); d1 = fmaf(cq1[7], hi.w, d1);
    d2 = fmaf(cq2[7], hi.w, d2); d3 = fmaf(cq3[7], hi.w, d3);
    float4 ov;
    ov.x = __fadd_rn(d0, bo); ov.y = __fadd_rn(d1, bo);
    ov.z = __fadd_rn(d2, bo); ov.w = __fadd_rn(d3, bo);
    op4[(size_t)d * (T_ / 4)] = ov;
  }
}

// ---------- finalize loss ----------
__global__ __launch_bounds__(64) void vq_fin(const float* __restrict__ lossp,
                                             float* __restrict__ oloss) {
  const int tid = threadIdx.x;
  if (tid < B_) {
    float s = 0.f;
    for (int i = 0; i < 16; ++i) s += lossp[tid * 16 + i];
    oloss[tid] = s * (1.25f / 32768.0f);
  }
}

extern "C" void kernel_launch(void* const* d_in, const int* in_sizes, int n_in,
                              void* d_out, int out_size, void* d_ws,
                              size_t ws_size, hipStream_t stream) {
  (void)in_sizes; (void)n_in; (void)out_size; (void)ws_size;
  const float* z = (const float*)d_in[0];
  const float* cb = (const float*)d_in[1];
  const float* g_in = (const float*)d_in[2];
  const float* v_in = (const float*)d_in[3];
  const float* b_in = (const float*)d_in[4];
  const float* g_out = (const float*)d_in[5];
  const float* v_out = (const float*)d_in[6];
  const float* b_out = (const float*)d_in[7];
  float* out = (float*)d_out;

  char* ws = (char*)d_ws;
  double* WTd = (double*)ws;              // 65536 B
  float* cb16 = (float*)(ws + 65536);     // 65536 B
  float* wo16 = (float*)(ws + 131072);    // 65536 B
  float* lossp = (float*)(ws + 196608);   // 1024 B

  float* oidx = out + (size_t)B_ * D_ * T_;
  float* oloss = oidx + (size_t)B_ * T_;

  vq_setup<<<1, 1024, 0, stream>>>(cb, g_in, v_in, g_out, v_out, b_out, WTd,
                                   cb16, wo16);
  vq_main<<<256, 1024, 0, stream>>>(z, cb, b_in, WTd, cb16, wo16, out, oidx,
                                    lossp);
  vq_fin<<<1, 64, 0, stream>>>(lossp, oloss);
}